// Round 2
// baseline (3164.038 us; speedup 1.0000x reference)
//
#include <hip/hip_runtime.h>
#include <math.h>

#define NE 1000000
#define DD 128
#define TWOD 256
#define H1C 256
#define H2C 128
#define EB 32
#define EPSLN 1e-5f

#define F4C(v,k) ((k)==0?(v).x:((k)==1?(v).y:((k)==2?(v).z:(v).w)))

__global__ __launch_bounds__(256, 4)
void decoder_fused(const float* __restrict__ nodes,
                   const float* __restrict__ nbrs,
                   const int*   __restrict__ eidx,
                   const float* __restrict__ g0, const float* __restrict__ be0,
                   const float* __restrict__ W1, const float* __restrict__ b1,
                   const float* __restrict__ g1, const float* __restrict__ be1,
                   const float* __restrict__ W2, const float* __restrict__ b2,
                   const float* __restrict__ g2, const float* __restrict__ be2,
                   const float* __restrict__ Wp, const float* __restrict__ bp,
                   const float* __restrict__ Ww, const float* __restrict__ bw,
                   const float* __restrict__ wnode, const float* __restrict__ wnbr,
                   float* __restrict__ out)
{
    __shared__ __align__(16) float xb[EB][TWOD];   // 32 KB staging (x, then h1)
    __shared__ float nbsim[EB];

    const int t    = threadIdx.x;
    const int wv   = t >> 6;     // wave 0..3
    const int lane = t & 63;
    const int rb   = t >> 5;     // 0..7  (row block of 4)
    const int cb   = t & 31;     // 0..31 (col block)
    const int e0   = blockIdx.x * EB;

    // ---------------- Stage 1: gather + combined + LN0 (fused) + nbrs_sim ----
    {
        const int c = 2 * lane;  // this lane's fixed columns: c,c+1 (sum half) / 128+c,129+c (prod half)
        const float2 g0s  = *(const float2*)(g0  + c);
        const float2 g0p  = *(const float2*)(g0  + DD + c);
        const float2 be0s = *(const float2*)(be0 + c);
        const float2 be0p = *(const float2*)(be0 + DD + c);
        #pragma unroll 2
        for (int ee = 0; ee < 8; ++ee) {
            const int el = wv * 8 + ee;
            const int e  = e0 + el;
            const int u  = eidx[e];
            const int v  = eidx[NE + e];
            const float2 nu = *(const float2*)(nodes + u * DD + c);
            const float2 nv = *(const float2*)(nodes + v * DD + c);
            const float2 bu = *(const float2*)(nbrs  + u * DD + c);
            const float2 bv = *(const float2*)(nbrs  + v * DD + c);
            const float sx = nu.x + nv.x, sy = nu.y + nv.y;
            const float px = nu.x * nv.x, py = nu.y * nv.y;
            float ps  = sx + sy + px + py;
            float pss = sx*sx + sy*sy + px*px + py*py;
            float pd  = bu.x * bv.x + bu.y * bv.y;
            #pragma unroll
            for (int m = 1; m < 64; m <<= 1) {
                ps  += __shfl_xor(ps,  m, 64);
                pss += __shfl_xor(pss, m, 64);
                pd  += __shfl_xor(pd,  m, 64);
            }
            const float mu  = ps  * (1.0f / 256.0f);
            const float var = pss * (1.0f / 256.0f) - mu * mu;
            const float inv = 1.0f / sqrtf(var + EPSLN);
            xb[el][c]          = (sx - mu) * inv * g0s.x + be0s.x;
            xb[el][c + 1]      = (sy - mu) * inv * g0s.y + be0s.y;
            xb[el][DD + c]     = (px - mu) * inv * g0p.x + be0p.x;
            xb[el][DD + c + 1] = (py - mu) * inv * g0p.y + be0p.y;
            if (lane == 0) nbsim[el] = pd;
        }
    }
    __syncthreads();

    const int r0 = rb * 4;

    // ---------------- GEMM1: [32,256] @ [256,256], 4x8 register tile ---------
    float acc[4][8];
    #pragma unroll
    for (int i = 0; i < 4; ++i)
        #pragma unroll
        for (int j = 0; j < 8; ++j) acc[i][j] = 0.0f;

    const int c1 = cb * 8;
    for (int k0 = 0; k0 < TWOD; k0 += 4) {
        float4 xv[4];
        #pragma unroll
        for (int i = 0; i < 4; ++i) xv[i] = *(const float4*)&xb[r0 + i][k0];
        #pragma unroll
        for (int kk = 0; kk < 4; ++kk) {
            const float4 wa  = *(const float4*)(W1 + (k0 + kk) * H1C + c1);
            const float4 wb4 = *(const float4*)(W1 + (k0 + kk) * H1C + c1 + 4);
            #pragma unroll
            for (int i = 0; i < 4; ++i) {
                const float x = F4C(xv[i], kk);
                acc[i][0] = fmaf(x, wa.x,  acc[i][0]);
                acc[i][1] = fmaf(x, wa.y,  acc[i][1]);
                acc[i][2] = fmaf(x, wa.z,  acc[i][2]);
                acc[i][3] = fmaf(x, wa.w,  acc[i][3]);
                acc[i][4] = fmaf(x, wb4.x, acc[i][4]);
                acc[i][5] = fmaf(x, wb4.y, acc[i][5]);
                acc[i][6] = fmaf(x, wb4.z, acc[i][6]);
                acc[i][7] = fmaf(x, wb4.w, acc[i][7]);
            }
        }
    }
    __syncthreads();   // all GEMM1 reads of xb complete

    // ---------------- bias + LN1 + ReLU, write h1 back into xb ---------------
    {
        const float4 b1a = *(const float4*)(b1  + c1);
        const float4 b1b = *(const float4*)(b1  + c1 + 4);
        const float4 g1a = *(const float4*)(g1  + c1);
        const float4 g1b = *(const float4*)(g1  + c1 + 4);
        const float4 e1a = *(const float4*)(be1 + c1);
        const float4 e1b = *(const float4*)(be1 + c1 + 4);
        #pragma unroll
        for (int i = 0; i < 4; ++i) {
            float v[8];
            v[0] = acc[i][0] + b1a.x; v[1] = acc[i][1] + b1a.y;
            v[2] = acc[i][2] + b1a.z; v[3] = acc[i][3] + b1a.w;
            v[4] = acc[i][4] + b1b.x; v[5] = acc[i][5] + b1b.y;
            v[6] = acc[i][6] + b1b.z; v[7] = acc[i][7] + b1b.w;
            float s = 0.0f, ss = 0.0f;
            #pragma unroll
            for (int j = 0; j < 8; ++j) { s += v[j]; ss += v[j] * v[j]; }
            #pragma unroll
            for (int m = 1; m < 32; m <<= 1) {
                s  += __shfl_xor(s,  m, 32);
                ss += __shfl_xor(ss, m, 32);
            }
            const float mu  = s  * (1.0f / 256.0f);
            const float var = ss * (1.0f / 256.0f) - mu * mu;
            const float inv = 1.0f / sqrtf(var + EPSLN);
            float o[8];
            o[0] = fmaxf(0.0f, (v[0]-mu)*inv*g1a.x + e1a.x);
            o[1] = fmaxf(0.0f, (v[1]-mu)*inv*g1a.y + e1a.y);
            o[2] = fmaxf(0.0f, (v[2]-mu)*inv*g1a.z + e1a.z);
            o[3] = fmaxf(0.0f, (v[3]-mu)*inv*g1a.w + e1a.w);
            o[4] = fmaxf(0.0f, (v[4]-mu)*inv*g1b.x + e1b.x);
            o[5] = fmaxf(0.0f, (v[5]-mu)*inv*g1b.y + e1b.y);
            o[6] = fmaxf(0.0f, (v[6]-mu)*inv*g1b.z + e1b.z);
            o[7] = fmaxf(0.0f, (v[7]-mu)*inv*g1b.w + e1b.w);
            *(float4*)&xb[r0 + i][c1]     = make_float4(o[0], o[1], o[2], o[3]);
            *(float4*)&xb[r0 + i][c1 + 4] = make_float4(o[4], o[5], o[6], o[7]);
        }
    }
    __syncthreads();   // h1 fully written

    // ---------------- GEMM2: [32,256] @ [256,128], 4x4 register tile ---------
    float ac2[4][4];
    #pragma unroll
    for (int i = 0; i < 4; ++i)
        #pragma unroll
        for (int j = 0; j < 4; ++j) ac2[i][j] = 0.0f;

    const int c2 = cb * 4;
    for (int k0 = 0; k0 < TWOD; k0 += 4) {
        float4 xv[4];
        #pragma unroll
        for (int i = 0; i < 4; ++i) xv[i] = *(const float4*)&xb[r0 + i][k0];
        #pragma unroll
        for (int kk = 0; kk < 4; ++kk) {
            const float4 w = *(const float4*)(W2 + (k0 + kk) * H2C + c2);
            #pragma unroll
            for (int i = 0; i < 4; ++i) {
                const float x = F4C(xv[i], kk);
                ac2[i][0] = fmaf(x, w.x, ac2[i][0]);
                ac2[i][1] = fmaf(x, w.y, ac2[i][1]);
                ac2[i][2] = fmaf(x, w.z, ac2[i][2]);
                ac2[i][3] = fmaf(x, w.w, ac2[i][3]);
            }
        }
    }

    // ---------------- bias + LN2 + ReLU + heads + outputs --------------------
    {
        const float4 b2v = *(const float4*)(b2  + c2);
        const float4 g2v = *(const float4*)(g2  + c2);
        const float4 e2v = *(const float4*)(be2 + c2);
        const float4 wpv = *(const float4*)(Wp  + c2);
        const float4 wwv = *(const float4*)(Ww  + c2);
        const float ww128 = Ww[DD];
        const float bpv = bp[0], bwv = bw[0];
        const float wn = wnode[0], wbr = wnbr[0];
        #pragma unroll
        for (int i = 0; i < 4; ++i) {
            float v0 = ac2[i][0] + b2v.x;
            float v1 = ac2[i][1] + b2v.y;
            float v2 = ac2[i][2] + b2v.z;
            float v3 = ac2[i][3] + b2v.w;
            float s  = v0 + v1 + v2 + v3;
            float ss = v0*v0 + v1*v1 + v2*v2 + v3*v3;
            #pragma unroll
            for (int m = 1; m < 32; m <<= 1) {
                s  += __shfl_xor(s,  m, 32);
                ss += __shfl_xor(ss, m, 32);
            }
            const float mu  = s  * (1.0f / 128.0f);
            const float var = ss * (1.0f / 128.0f) - mu * mu;
            const float inv = 1.0f / sqrtf(var + EPSLN);
            const float h0  = fmaxf(0.0f, (v0-mu)*inv*g2v.x + e2v.x);
            const float h1v = fmaxf(0.0f, (v1-mu)*inv*g2v.y + e2v.y);
            const float h2v = fmaxf(0.0f, (v2-mu)*inv*g2v.z + e2v.z);
            const float h3  = fmaxf(0.0f, (v3-mu)*inv*g2v.w + e2v.w);
            float pdot = h0*wpv.x + h1v*wpv.y + h2v*wpv.z + h3*wpv.w;
            float wdot = h0*wwv.x + h1v*wwv.y + h2v*wwv.z + h3*wwv.w;
            #pragma unroll
            for (int m = 1; m < 32; m <<= 1) {
                pdot += __shfl_xor(pdot, m, 32);
                wdot += __shfl_xor(wdot, m, 32);
            }
            if (cb == 0) {
                const int e  = e0 + r0 + i;
                const float ns   = nbsim[r0 + i];
                const float nc   = (pdot + bpv) * wn;
                const float nbc  = ns * wbr;
                const float prob = nc + nbc;
                out[e]          = prob;
                out[NE + e]     = fmaxf(0.0f, wdot + ns * ww128 + bwv);
                out[2 * NE + e] = nc / (prob + 1e-8f);
            }
        }
    }
}

extern "C" void kernel_launch(void* const* d_in, const int* in_sizes, int n_in,
                              void* d_out, int out_size, void* d_ws, size_t ws_size,
                              hipStream_t stream) {
    const float* nodes = (const float*)d_in[0];
    const float* nbrs  = (const float*)d_in[1];
    const int*   eidx  = (const int*)d_in[2];
    const float* g0    = (const float*)d_in[3];
    const float* be0   = (const float*)d_in[4];
    const float* W1    = (const float*)d_in[5];
    const float* b1    = (const float*)d_in[6];
    const float* g1    = (const float*)d_in[7];
    const float* be1   = (const float*)d_in[8];
    const float* W2    = (const float*)d_in[9];
    const float* b2    = (const float*)d_in[10];
    const float* g2    = (const float*)d_in[11];
    const float* be2   = (const float*)d_in[12];
    const float* Wp    = (const float*)d_in[13];
    const float* bp    = (const float*)d_in[14];
    const float* Ww    = (const float*)d_in[15];
    const float* bw    = (const float*)d_in[16];
    const float* wnode = (const float*)d_in[17];
    const float* wnbr  = (const float*)d_in[18];
    float* out = (float*)d_out;

    dim3 grid(NE / EB), block(256);
    decoder_fused<<<grid, block, 0, stream>>>(nodes, nbrs, eidx, g0, be0,
                                              W1, b1, g1, be1, W2, b2, g2, be2,
                                              Wp, bp, Ww, bw, wnode, wnbr, out);
}

// Round 3
// 2634.331 us; speedup vs baseline: 1.2011x; 1.2011x over previous
//
#include <hip/hip_runtime.h>
#include <math.h>

#define NE 1000000
#define DD 128
#define TWOD 256
#define H1C 256
#define H2C 128
#define EB 64
#define EPSLN 1e-5f

typedef float f32x2 __attribute__((ext_vector_type(2)));
typedef float f32x4 __attribute__((ext_vector_type(4)));

#define LO2(q) __builtin_shufflevector((q), (q), 0, 1)
#define HI2(q) __builtin_shufflevector((q), (q), 2, 3)

// c += broadcast(x.lo) * w   (both halves of result use low dword of x)
__device__ __forceinline__ void pk_fma_b0(f32x2& c, f32x2 x, f32x2 w) {
    asm("v_pk_fma_f32 %0, %1, %2, %0 op_sel:[0,0,0] op_sel_hi:[0,1,1]"
        : "+v"(c) : "v"(x), "v"(w));
}
// c += broadcast(x.hi) * w
__device__ __forceinline__ void pk_fma_b1(f32x2& c, f32x2 x, f32x2 w) {
    asm("v_pk_fma_f32 %0, %1, %2, %0 op_sel:[1,0,0] op_sel_hi:[1,1,1]"
        : "+v"(c) : "v"(x), "v"(w));
}

__global__ __launch_bounds__(256, 2)
void decoder_fused(const float* __restrict__ nodes,
                   const float* __restrict__ nbrs,
                   const int*   __restrict__ eidx,
                   const float* __restrict__ g0, const float* __restrict__ be0,
                   const float* __restrict__ W1, const float* __restrict__ b1,
                   const float* __restrict__ g1, const float* __restrict__ be1,
                   const float* __restrict__ W2, const float* __restrict__ b2,
                   const float* __restrict__ g2, const float* __restrict__ be2,
                   const float* __restrict__ Wp, const float* __restrict__ bp,
                   const float* __restrict__ Ww, const float* __restrict__ bw,
                   const float* __restrict__ wnode, const float* __restrict__ wnbr,
                   float* __restrict__ out)
{
    __shared__ __align__(16) float xb[EB][TWOD];   // 64 KB staging (x, then h1)
    __shared__ float nbsim[EB];

    const int t    = threadIdx.x;
    const int wv   = t >> 6;     // wave 0..3
    const int lane = t & 63;
    const int rb   = t >> 5;     // 0..7  (row block of 8)
    const int cb   = t & 31;     // 0..31 (col block)
    const int e0   = blockIdx.x * EB;

    // ---------------- Stage 1: gather + combined + LN0 (fused) + nbrs_sim ----
    {
        const int c = 2 * lane;
        const float2 g0s  = *(const float2*)(g0  + c);
        const float2 g0p  = *(const float2*)(g0  + DD + c);
        const float2 be0s = *(const float2*)(be0 + c);
        const float2 be0p = *(const float2*)(be0 + DD + c);
        #pragma unroll 2
        for (int ee = 0; ee < 16; ++ee) {
            const int el = wv * 16 + ee;
            const int e  = e0 + el;
            const int u  = eidx[e];
            const int v  = eidx[NE + e];
            const float2 nu = *(const float2*)(nodes + u * DD + c);
            const float2 nv = *(const float2*)(nodes + v * DD + c);
            const float2 bu = *(const float2*)(nbrs  + u * DD + c);
            const float2 bv = *(const float2*)(nbrs  + v * DD + c);
            const float sx = nu.x + nv.x, sy = nu.y + nv.y;
            const float px = nu.x * nv.x, py = nu.y * nv.y;
            float ps  = sx + sy + px + py;
            float pss = sx*sx + sy*sy + px*px + py*py;
            float pd  = bu.x * bv.x + bu.y * bv.y;
            #pragma unroll
            for (int m = 1; m < 64; m <<= 1) {
                ps  += __shfl_xor(ps,  m, 64);
                pss += __shfl_xor(pss, m, 64);
                pd  += __shfl_xor(pd,  m, 64);
            }
            const float mu  = ps  * (1.0f / 256.0f);
            const float var = pss * (1.0f / 256.0f) - mu * mu;
            const float inv = 1.0f / sqrtf(var + EPSLN);
            xb[el][c]          = (sx - mu) * inv * g0s.x + be0s.x;
            xb[el][c + 1]      = (sy - mu) * inv * g0s.y + be0s.y;
            xb[el][DD + c]     = (px - mu) * inv * g0p.x + be0p.x;
            xb[el][DD + c + 1] = (py - mu) * inv * g0p.y + be0p.y;
            if (lane == 0) nbsim[el] = pd;
        }
    }
    __syncthreads();

    const int r0 = rb * 8;

    // ---------------- GEMM1: [64,256] @ [256,256], 8 rows x 4 col-pairs -----
    f32x2 acc1[8][4];
    #pragma unroll
    for (int i = 0; i < 8; ++i)
        #pragma unroll
        for (int p = 0; p < 4; ++p) acc1[i][p] = f32x2{0.0f, 0.0f};

    const int c1 = cb * 8;
    {
        const float* __restrict__ w1p = W1 + c1;
        f32x4 c00 = *(const f32x4*)(w1p);
        f32x4 c01 = *(const f32x4*)(w1p + 4);
        f32x4 c10 = *(const f32x4*)(w1p + H1C);
        f32x4 c11 = *(const f32x4*)(w1p + H1C + 4);
        f32x4 c20 = *(const f32x4*)(w1p + 2 * H1C);
        f32x4 c21 = *(const f32x4*)(w1p + 2 * H1C + 4);
        f32x4 c30 = *(const f32x4*)(w1p + 3 * H1C);
        f32x4 c31 = *(const f32x4*)(w1p + 3 * H1C + 4);

        #pragma unroll 2
        for (int k0 = 0; k0 < TWOD; k0 += 4) {
            f32x2 xp0[8], xp1[8];
            #pragma unroll
            for (int i = 0; i < 8; ++i) {
                f32x4 q = *(const f32x4*)&xb[r0 + i][k0];
                xp0[i] = LO2(q); xp1[i] = HI2(q);
            }
            const int kn = (k0 + 4) & 255;   // cyclic: last prefetch harmless
            const float* wnp = w1p + kn * H1C;
            f32x4 n00 = *(const f32x4*)(wnp);
            f32x4 n01 = *(const f32x4*)(wnp + 4);
            f32x4 n10 = *(const f32x4*)(wnp + H1C);
            f32x4 n11 = *(const f32x4*)(wnp + H1C + 4);
            f32x4 n20 = *(const f32x4*)(wnp + 2 * H1C);
            f32x4 n21 = *(const f32x4*)(wnp + 2 * H1C + 4);
            f32x4 n30 = *(const f32x4*)(wnp + 3 * H1C);
            f32x4 n31 = *(const f32x4*)(wnp + 3 * H1C + 4);

            f32x2 wA, wB, wC, wD;
            // kk = 0: broadcast lo of xp0
            wA = LO2(c00); wB = HI2(c00); wC = LO2(c01); wD = HI2(c01);
            #pragma unroll
            for (int i = 0; i < 8; ++i) {
                pk_fma_b0(acc1[i][0], xp0[i], wA);
                pk_fma_b0(acc1[i][1], xp0[i], wB);
                pk_fma_b0(acc1[i][2], xp0[i], wC);
                pk_fma_b0(acc1[i][3], xp0[i], wD);
            }
            // kk = 1: broadcast hi of xp0
            wA = LO2(c10); wB = HI2(c10); wC = LO2(c11); wD = HI2(c11);
            #pragma unroll
            for (int i = 0; i < 8; ++i) {
                pk_fma_b1(acc1[i][0], xp0[i], wA);
                pk_fma_b1(acc1[i][1], xp0[i], wB);
                pk_fma_b1(acc1[i][2], xp0[i], wC);
                pk_fma_b1(acc1[i][3], xp0[i], wD);
            }
            // kk = 2: broadcast lo of xp1
            wA = LO2(c20); wB = HI2(c20); wC = LO2(c21); wD = HI2(c21);
            #pragma unroll
            for (int i = 0; i < 8; ++i) {
                pk_fma_b0(acc1[i][0], xp1[i], wA);
                pk_fma_b0(acc1[i][1], xp1[i], wB);
                pk_fma_b0(acc1[i][2], xp1[i], wC);
                pk_fma_b0(acc1[i][3], xp1[i], wD);
            }
            // kk = 3: broadcast hi of xp1
            wA = LO2(c30); wB = HI2(c30); wC = LO2(c31); wD = HI2(c31);
            #pragma unroll
            for (int i = 0; i < 8; ++i) {
                pk_fma_b1(acc1[i][0], xp1[i], wA);
                pk_fma_b1(acc1[i][1], xp1[i], wB);
                pk_fma_b1(acc1[i][2], xp1[i], wC);
                pk_fma_b1(acc1[i][3], xp1[i], wD);
            }
            c00 = n00; c01 = n01; c10 = n10; c11 = n11;
            c20 = n20; c21 = n21; c30 = n30; c31 = n31;
        }
    }
    __syncthreads();   // all GEMM1 reads of xb complete

    // ---------------- bias + LN1 + ReLU, write h1 back into xb ---------------
    {
        const float4 b1a = *(const float4*)(b1  + c1);
        const float4 b1b = *(const float4*)(b1  + c1 + 4);
        const float4 g1a = *(const float4*)(g1  + c1);
        const float4 g1b = *(const float4*)(g1  + c1 + 4);
        const float4 e1a = *(const float4*)(be1 + c1);
        const float4 e1b = *(const float4*)(be1 + c1 + 4);
        #pragma unroll
        for (int i = 0; i < 8; ++i) {
            float v[8];
            v[0] = acc1[i][0].x + b1a.x; v[1] = acc1[i][0].y + b1a.y;
            v[2] = acc1[i][1].x + b1a.z; v[3] = acc1[i][1].y + b1a.w;
            v[4] = acc1[i][2].x + b1b.x; v[5] = acc1[i][2].y + b1b.y;
            v[6] = acc1[i][3].x + b1b.z; v[7] = acc1[i][3].y + b1b.w;
            float s = 0.0f, ss = 0.0f;
            #pragma unroll
            for (int j = 0; j < 8; ++j) { s += v[j]; ss += v[j] * v[j]; }
            #pragma unroll
            for (int m = 1; m < 32; m <<= 1) {
                s  += __shfl_xor(s,  m, 32);
                ss += __shfl_xor(ss, m, 32);
            }
            const float mu  = s  * (1.0f / 256.0f);
            const float var = ss * (1.0f / 256.0f) - mu * mu;
            const float inv = 1.0f / sqrtf(var + EPSLN);
            float o[8];
            o[0] = fmaxf(0.0f, (v[0]-mu)*inv*g1a.x + e1a.x);
            o[1] = fmaxf(0.0f, (v[1]-mu)*inv*g1a.y + e1a.y);
            o[2] = fmaxf(0.0f, (v[2]-mu)*inv*g1a.z + e1a.z);
            o[3] = fmaxf(0.0f, (v[3]-mu)*inv*g1a.w + e1a.w);
            o[4] = fmaxf(0.0f, (v[4]-mu)*inv*g1b.x + e1b.x);
            o[5] = fmaxf(0.0f, (v[5]-mu)*inv*g1b.y + e1b.y);
            o[6] = fmaxf(0.0f, (v[6]-mu)*inv*g1b.z + e1b.z);
            o[7] = fmaxf(0.0f, (v[7]-mu)*inv*g1b.w + e1b.w);
            *(float4*)&xb[r0 + i][c1]     = make_float4(o[0], o[1], o[2], o[3]);
            *(float4*)&xb[r0 + i][c1 + 4] = make_float4(o[4], o[5], o[6], o[7]);
        }
    }
    __syncthreads();   // h1 fully written

    // ---------------- GEMM2: [64,256] @ [256,128], 8 rows x 2 col-pairs -----
    f32x2 acc2[8][2];
    #pragma unroll
    for (int i = 0; i < 8; ++i) {
        acc2[i][0] = f32x2{0.0f, 0.0f};
        acc2[i][1] = f32x2{0.0f, 0.0f};
    }

    const int c2 = cb * 4;
    {
        const float* __restrict__ w2p = W2 + c2;
        f32x4 d0 = *(const f32x4*)(w2p);
        f32x4 d1 = *(const f32x4*)(w2p + H2C);
        f32x4 d2 = *(const f32x4*)(w2p + 2 * H2C);
        f32x4 d3 = *(const f32x4*)(w2p + 3 * H2C);

        #pragma unroll 2
        for (int k0 = 0; k0 < TWOD; k0 += 4) {
            f32x2 xp0[8], xp1[8];
            #pragma unroll
            for (int i = 0; i < 8; ++i) {
                f32x4 q = *(const f32x4*)&xb[r0 + i][k0];
                xp0[i] = LO2(q); xp1[i] = HI2(q);
            }
            const int kn = (k0 + 4) & 255;
            const float* wnp = w2p + kn * H2C;
            f32x4 m0 = *(const f32x4*)(wnp);
            f32x4 m1 = *(const f32x4*)(wnp + H2C);
            f32x4 m2 = *(const f32x4*)(wnp + 2 * H2C);
            f32x4 m3 = *(const f32x4*)(wnp + 3 * H2C);

            f32x2 wA, wB;
            wA = LO2(d0); wB = HI2(d0);
            #pragma unroll
            for (int i = 0; i < 8; ++i) {
                pk_fma_b0(acc2[i][0], xp0[i], wA);
                pk_fma_b0(acc2[i][1], xp0[i], wB);
            }
            wA = LO2(d1); wB = HI2(d1);
            #pragma unroll
            for (int i = 0; i < 8; ++i) {
                pk_fma_b1(acc2[i][0], xp0[i], wA);
                pk_fma_b1(acc2[i][1], xp0[i], wB);
            }
            wA = LO2(d2); wB = HI2(d2);
            #pragma unroll
            for (int i = 0; i < 8; ++i) {
                pk_fma_b0(acc2[i][0], xp1[i], wA);
                pk_fma_b0(acc2[i][1], xp1[i], wB);
            }
            wA = LO2(d3); wB = HI2(d3);
            #pragma unroll
            for (int i = 0; i < 8; ++i) {
                pk_fma_b1(acc2[i][0], xp1[i], wA);
                pk_fma_b1(acc2[i][1], xp1[i], wB);
            }
            d0 = m0; d1 = m1; d2 = m2; d3 = m3;
        }
    }

    // ---------------- bias + LN2 + ReLU + heads + outputs --------------------
    {
        const float4 b2v = *(const float4*)(b2  + c2);
        const float4 g2v = *(const float4*)(g2  + c2);
        const float4 e2v = *(const float4*)(be2 + c2);
        const float4 wpv = *(const float4*)(Wp  + c2);
        const float4 wwv = *(const float4*)(Ww  + c2);
        const float ww128 = Ww[DD];
        const float bpv = bp[0], bwv = bw[0];
        const float wn = wnode[0], wbr = wnbr[0];
        #pragma unroll
        for (int i = 0; i < 8; ++i) {
            float v0 = acc2[i][0].x + b2v.x;
            float v1 = acc2[i][0].y + b2v.y;
            float v2 = acc2[i][1].x + b2v.z;
            float v3 = acc2[i][1].y + b2v.w;
            float s  = v0 + v1 + v2 + v3;
            float ss = v0*v0 + v1*v1 + v2*v2 + v3*v3;
            #pragma unroll
            for (int m = 1; m < 32; m <<= 1) {
                s  += __shfl_xor(s,  m, 32);
                ss += __shfl_xor(ss, m, 32);
            }
            const float mu  = s  * (1.0f / 128.0f);
            const float var = ss * (1.0f / 128.0f) - mu * mu;
            const float inv = 1.0f / sqrtf(var + EPSLN);
            const float h0  = fmaxf(0.0f, (v0-mu)*inv*g2v.x + e2v.x);
            const float h1v = fmaxf(0.0f, (v1-mu)*inv*g2v.y + e2v.y);
            const float h2v = fmaxf(0.0f, (v2-mu)*inv*g2v.z + e2v.z);
            const float h3  = fmaxf(0.0f, (v3-mu)*inv*g2v.w + e2v.w);
            float pdot = h0*wpv.x + h1v*wpv.y + h2v*wpv.z + h3*wpv.w;
            float wdot = h0*wwv.x + h1v*wwv.y + h2v*wwv.z + h3*wwv.w;
            #pragma unroll
            for (int m = 1; m < 32; m <<= 1) {
                pdot += __shfl_xor(pdot, m, 32);
                wdot += __shfl_xor(wdot, m, 32);
            }
            if (cb == 0) {
                const int e  = e0 + r0 + i;
                const float ns   = nbsim[r0 + i];
                const float nc   = (pdot + bpv) * wn;
                const float nbc  = ns * wbr;
                const float prob = nc + nbc;
                out[e]          = prob;
                out[NE + e]     = fmaxf(0.0f, wdot + ns * ww128 + bwv);
                out[2 * NE + e] = nc / (prob + 1e-8f);
            }
        }
    }
}

extern "C" void kernel_launch(void* const* d_in, const int* in_sizes, int n_in,
                              void* d_out, int out_size, void* d_ws, size_t ws_size,
                              hipStream_t stream) {
    const float* nodes = (const float*)d_in[0];
    const float* nbrs  = (const float*)d_in[1];
    const int*   eidx  = (const int*)d_in[2];
    const float* g0    = (const float*)d_in[3];
    const float* be0   = (const float*)d_in[4];
    const float* W1    = (const float*)d_in[5];
    const float* b1    = (const float*)d_in[6];
    const float* g1    = (const float*)d_in[7];
    const float* be1   = (const float*)d_in[8];
    const float* W2    = (const float*)d_in[9];
    const float* b2    = (const float*)d_in[10];
    const float* g2    = (const float*)d_in[11];
    const float* be2   = (const float*)d_in[12];
    const float* Wp    = (const float*)d_in[13];
    const float* bp    = (const float*)d_in[14];
    const float* Ww    = (const float*)d_in[15];
    const float* bw    = (const float*)d_in[16];
    const float* wnode = (const float*)d_in[17];
    const float* wnbr  = (const float*)d_in[18];
    float* out = (float*)d_out;

    dim3 grid(NE / EB), block(256);
    decoder_fused<<<grid, block, 0, stream>>>(nodes, nbrs, eidx, g0, be0,
                                              W1, b1, g1, be1, W2, b2, g2, be2,
                                              Wp, bp, Ww, bw, wnode, wnbr, out);
}